// Round 2
// baseline (687.123 us; speedup 1.0000x reference)
//
#include <hip/hip_runtime.h>

// Adaptive avg pool 64x64 -> 6x6, fp32, N=16, C=2048 (32768 planes).
// Bin edges (compile-time): starts {0,10,21,32,42,53}, ends {11,22,32,43,54,64}
// (adjacent bins OVERLAP by one row/col at 10,21,42,53; widths 11/12).
//
// One WAVE owns a plane; zero barriers; software-pipelined 1-deep:
//   iteration body = [accumulate plane p from in-flight regs]
//                    [issue 16 dwordx4 loads for plane p+1]   <- in flight across fence
//                    [ds_write 2 partials -> parity slab; lgkmcnt(0) fence]
//                    [48-lane W-bin reduction; shfl-merge; store p]
// Loads use vmcnt, fence waits lgkmcnt only -> next-plane HBM latency hides
// under the LDS phase + cross-wave TLP (16 waves/CU resident).
//
// Row->bin mapping: lane l: row-group g=l>>4 (rows 16g..16g+15), f4-col c=l&15.
// Each row-group spans exactly 2 H-bins, split at local row 11 (g even) or
// 6 (g odd), with the boundary row shared. Shared-prefix accumulate:
//   s_lo=t0..4, s_mid=t6..9, s_hi=t11..15, M=s_mid+(even?t10:t5)
//   a = s_lo+t5+(even?M:0)   b = s_hi+t10+(even?0:M)
// Slot layout (per-wave, 8 x 68f): slot 2g = first part, 2g+1 = second.
//   bin0=s0, bin1=s1+s2, bin2=s3, bin3=s4, bin4=s5+s6, bin5=s7.

#define H_IN 64
#define W_IN 64
#define SLOT_STRIDE 68      // floats; 272 B: 16B-aligned writes, bank-spread reads
#define WPB 4               // waves per block

__global__ __launch_bounds__(256, 4)
void adaptive_pool_kernel(const float* __restrict__ x,
                          float* __restrict__ out,
                          const int n_planes) {
    __shared__ float lds[WPB][2][8][SLOT_STRIDE];   // 17408 B / block

    const int tid  = threadIdx.x;
    const int lane = tid & 63;
    const int wid  = tid >> 6;
    const int g    = lane >> 4;
    const int c    = lane & 15;
    const bool g_even = ((g & 1) == 0);

    // ---- loop-invariant reduction-task descriptors ----
    // lanes 0..35: output bin (i,j), first slot. lanes 36..47: second slot of
    // bins i=1 (lanes 36..41) / i=4 (lanes 42..47). lanes 48..63: idle-safe.
    int slot = 0, bsj = 0, partner = 0;
    bool wide = false, hasPartner = false, isOut = false;
    float scale = 0.f;
    if (lane < 36) {
        const int i = lane / 6, j = lane - 6 * i;
        slot = i + (i + 1) / 3;                  // {0,1,3,4,5,7}
        bsj  = (j * 64) / 6;                     // {0,10,21,32,42,53}
        wide = (j == 1 || j == 4);               // width 12 bins
        hasPartner = (i == 1 || i == 4);
        partner = (i == 1 ? 36 : 42) + j;
        const int bsi = (i * 64) / 6;
        const int bei = ((i + 1) * 64 + 5) / 6;
        const int bej = ((j + 1) * 64 + 5) / 6;
        scale = 1.0f / (float)((bei - bsi) * (bej - bsj));
        isOut = true;
    } else if (lane < 48) {
        const int j = (lane < 42) ? lane - 36 : lane - 42;
        slot = (lane < 42) ? 2 : 6;
        bsj  = (j * 64) / 6;
        wide = (j == 1 || j == 4);
    }

    const int gw = blockIdx.x * WPB + wid;       // global wave id
    const int nw = gridDim.x * WPB;              // 4096
    float* const Lbase = &lds[wid][0][0][0];

    int plane = gw;
    if (plane >= n_planes) return;

    // ---- prologue: issue first plane's loads ----
    const float4* __restrict__ p4 =
        (const float4*)(x + (size_t)plane * (H_IN * W_IN)) + (g * 256 + c);
    float4 v[16];
    #pragma unroll
    for (int t = 0; t < 16; ++t) v[t] = p4[t * 16];   // byte offs t*256, imm-folded

    int parity = 0;
    while (true) {
        // ---- accumulate plane p: rows -> two H-bin partials a,b ----
        float4 s_lo = v[0];
        { s_lo.x+=v[1].x+v[2].x+v[3].x+v[4].x; s_lo.y+=v[1].y+v[2].y+v[3].y+v[4].y;
          s_lo.z+=v[1].z+v[2].z+v[3].z+v[4].z; s_lo.w+=v[1].w+v[2].w+v[3].w+v[4].w; }
        float4 s_mid = v[6];
        { s_mid.x+=v[7].x+v[8].x+v[9].x; s_mid.y+=v[7].y+v[8].y+v[9].y;
          s_mid.z+=v[7].z+v[8].z+v[9].z; s_mid.w+=v[7].w+v[8].w+v[9].w; }
        float4 s_hi = v[11];
        { s_hi.x+=v[12].x+v[13].x+v[14].x+v[15].x; s_hi.y+=v[12].y+v[13].y+v[14].y+v[15].y;
          s_hi.z+=v[12].z+v[13].z+v[14].z+v[15].z; s_hi.w+=v[12].w+v[13].w+v[14].w+v[15].w; }
        const float4 t5 = v[5], t10 = v[10];
        float4 M;   // s_mid + boundary row of the "other" side
        M.x = s_mid.x + (g_even ? t10.x : t5.x);
        M.y = s_mid.y + (g_even ? t10.y : t5.y);
        M.z = s_mid.z + (g_even ? t10.z : t5.z);
        M.w = s_mid.w + (g_even ? t10.w : t5.w);
        float4 a, b;
        a.x = s_lo.x + t5.x + (g_even ? M.x : 0.f);
        a.y = s_lo.y + t5.y + (g_even ? M.y : 0.f);
        a.z = s_lo.z + t5.z + (g_even ? M.z : 0.f);
        a.w = s_lo.w + t5.w + (g_even ? M.w : 0.f);
        b.x = s_hi.x + t10.x + (g_even ? 0.f : M.x);
        b.y = s_hi.y + t10.y + (g_even ? 0.f : M.y);
        b.z = s_hi.z + t10.z + (g_even ? 0.f : M.z);
        b.w = s_hi.w + t10.w + (g_even ? 0.f : M.w);

        // ---- issue plane p+1's loads (stay in flight across the lgkm fence) ----
        const int next = plane + nw;
        if (next < n_planes) {
            p4 = (const float4*)(x + (size_t)next * (H_IN * W_IN)) + (g * 256 + c);
            #pragma unroll
            for (int t = 0; t < 16; ++t) v[t] = p4[t * 16];
        }

        // ---- per-wave column sums into parity slab ----
        float* const Lb = Lbase + parity * (8 * SLOT_STRIDE);
        *(float4*)&Lb[(2 * g    ) * SLOT_STRIDE + 4 * c] = a;
        *(float4*)&Lb[(2 * g + 1) * SLOT_STRIDE + 4 * c] = b;
        // Same-wave cross-lane LDS visibility (DS completes in-order per wave).
        // lgkmcnt only: the global loads above remain in flight (vmcnt).
        asm volatile("s_waitcnt lgkmcnt(0)" ::: "memory");

        // ---- 48-lane W-bin reduction (11 reads + 1 masked) ----
        const float* __restrict__ row = &Lb[slot * SLOT_STRIDE + bsj];
        float s = 0.f;
        #pragma unroll
        for (int k = 0; k < 11; ++k) s += row[k];
        if (wide) s += row[11];
        const float ps = __shfl(s, partner);     // second-slot partial
        if (isOut) {
            const float r = hasPartner ? (s + ps) : s;
            out[(size_t)plane * 36 + lane] = r * scale;
        }

        if (next >= n_planes) break;
        plane = next;
        parity ^= 1;
    }
}

extern "C" void kernel_launch(void* const* d_in, const int* in_sizes, int n_in,
                              void* d_out, int out_size, void* d_ws, size_t ws_size,
                              hipStream_t stream) {
    const float* x = (const float*)d_in[0];
    float* out = (float*)d_out;
    const int n_planes = in_sizes[0] / (H_IN * W_IN);   // 16*2048 = 32768
    adaptive_pool_kernel<<<1024, 256, 0, stream>>>(x, out, n_planes);
}